// Round 6
// baseline (12444.288 us; speedup 1.0000x reference)
//
#include <hip/hip_runtime.h>
#include <math.h>

// Elman RNN persistent kernel, R6: direct-to-register dataflow.
// batch=64, T=2048, in=256, hidden=512, out=256, fp32.
// 256 blocks = 4 batch-groups(16 rows) x 64 col-groups(8 h-cols, 4 y-cols).
// Thread (r2=tid>>5, g=tid&31): owns rows {r2,r2+8} x k-slice {128j+4g+i}.
//   w1r[6][4][8] (K=768 incl x), w2r[4][4][4]  -> weights permanent in regs
//   hreg[2][4] float4 = its 32 h floats, loaded DIRECTLY from hbuf (no LDS)
//   xreg[2][2] float4 = its 16 x floats (plain cached loads, L2-shared)
// Per-wave tags (monotonic, init 0): producer wave stores h, vmcnt(0), lane0
// publishes tag=t+1. Consumers poll >=t. 2 barriers/step. LDS = reduce
// scratch only (24KB). Sync protocol: relaxed-agent everywhere (R3/R5 proven).
// Numerics: recurrence MUST stay fp32 (error amplification ~1e4, R1);
// h exchange is bit-exact (no tag-in-data tricks).

#define BB 64
#define TT 2048
#define II 256
#define HH 512
#define OO 256
#define NBLK 256
#define OUT_OFF ((size_t)BB * TT * OO)
#define NTAGS (4 * 64 * 2)

typedef unsigned long long ull;
#define F4C(v,i) ((i)==0?(v).x:((i)==1?(v).y:((i)==2?(v).z:(v).w)))

__global__ void rnn_init(int* __restrict__ tags) {
    int i = blockIdx.x * blockDim.x + threadIdx.x;
    if (i < NTAGS) tags[i] = 0;
}

__device__ inline float4 ld_h4(const ull* p) {
    ull a = __hip_atomic_load(p,     __ATOMIC_RELAXED, __HIP_MEMORY_SCOPE_AGENT);
    ull b = __hip_atomic_load(p + 1, __ATOMIC_RELAXED, __HIP_MEMORY_SCOPE_AGENT);
    float2 lo = __builtin_bit_cast(float2, a);
    float2 hi = __builtin_bit_cast(float2, b);
    return make_float4(lo.x, lo.y, hi.x, hi.y);
}

__global__ __launch_bounds__(256, 1) void rnn_persist(
    const float* __restrict__ x, const float* __restrict__ W1,
    const float* __restrict__ b1, const float* __restrict__ W2,
    const float* __restrict__ b2, float* __restrict__ out,
    int* __restrict__ tags, float* __restrict__ hbuf)
{
    __shared__ float sc_h[16 * 8 * 32];   // 16KB: h partials, 32 per output
    __shared__ float sc_y[16 * 4 * 32];   //  8KB: y partials

    const int tid = threadIdx.x;
    const int blk = blockIdx.x;
    const int bi  = blk >> 6;             // batch group (16 rows)
    const int cj  = blk & 63;             // col group
    const int R0  = bi << 4;
    const int C0  = cj << 3;              // 8 h-cols
    const int O0  = cj << 2;              // 4 y-cols

    const int g  = tid & 31;              // k-slice
    const int r2 = tid >> 5;              // rows r2, r2+8
    const int oc = tid & 7;               // h-finish col (tid<128)
    const int yi = tid - 128, yo = yi & 3, yrow = yi >> 2; // y-finish (128..191)

    // ---- weights into registers (one-time) ----
    float w1r[6][4][8];
    #pragma unroll
    for (int j = 0; j < 6; ++j)
        #pragma unroll
        for (int i = 0; i < 4; ++i) {
            const float* wp = W1 + (size_t)(j * 128 + (g << 2) + i) * HH + C0;
            float4 a = *(const float4*)wp;
            float4 b = *(const float4*)(wp + 4);
            w1r[j][i][0] = a.x; w1r[j][i][1] = a.y; w1r[j][i][2] = a.z; w1r[j][i][3] = a.w;
            w1r[j][i][4] = b.x; w1r[j][i][5] = b.y; w1r[j][i][6] = b.z; w1r[j][i][7] = b.w;
        }
    float w2r[4][4][4];
    #pragma unroll
    for (int j = 0; j < 4; ++j)
        #pragma unroll
        for (int i = 0; i < 4; ++i) {
            float4 a = *(const float4*)(W2 + (size_t)(j * 128 + (g << 2) + i) * OO + O0);
            w2r[j][i][0] = a.x; w2r[j][i][1] = a.y; w2r[j][i][2] = a.z; w2r[j][i][3] = a.w;
        }
    const float b1v = (tid < 128) ? b1[C0 + oc] : 0.f;
    const float b2v = (tid >= 128 && tid < 192) ? b2[O0 + yo] : 0.f;

    ull* hb[2] = { (ull*)hbuf, (ull*)(hbuf + (size_t)BB * HH) };
    int* mytag = &tags[((bi << 6) + cj) * 2];      // producer side (2 waves)
    const int* ptag = &tags[((bi << 6) + (tid >> 1)) * 2 + (tid & 1)]; // poll side

    for (int t = 0; t < TT; ++t) {
        // ---- x_t direct-to-reg (issued before poll; latency overlaps) ----
        float4 xreg[2][2];
        #pragma unroll
        for (int rr = 0; rr < 2; ++rr)
            #pragma unroll
            for (int jx = 0; jx < 2; ++jx)
                xreg[rr][jx] = *(const float4*)&x[((size_t)(R0 + r2 + (rr << 3)) * TT + t) * II
                                                  + jx * 128 + (g << 2)];
        // ---- wait + load h_t direct-to-reg ----
        float4 hreg[2][4];
        if (t > 0) {
            if (tid < 128)
                while (__hip_atomic_load(ptag, __ATOMIC_RELAXED,
                                         __HIP_MEMORY_SCOPE_AGENT) < t) {}
            __syncthreads();                       // SYNC-poll
            const ull* hsrc = hb[t & 1];
            #pragma unroll
            for (int rr = 0; rr < 2; ++rr) {
                const ull* rp = hsrc + (size_t)(R0 + r2 + (rr << 3)) * (HH / 2) + (g << 1);
                #pragma unroll
                for (int j = 0; j < 4; ++j)
                    hreg[rr][j] = ld_h4(rp + j * 64);
            }
        } else {
            #pragma unroll
            for (int rr = 0; rr < 2; ++rr)
                #pragma unroll
                for (int j = 0; j < 4; ++j)
                    hreg[rr][j] = make_float4(0.f, 0.f, 0.f, 0.f);
            __syncthreads();
        }

        // ---- A-GEMM (K=768) and Y-GEMM (K=512) from regs ----
        float pa[2][8];
        float py[2][4];
        #pragma unroll
        for (int rr = 0; rr < 2; ++rr) {
            #pragma unroll
            for (int c = 0; c < 8; ++c) pa[rr][c] = 0.f;
            #pragma unroll
            for (int o = 0; o < 4; ++o) py[rr][o] = 0.f;
        }
        #pragma unroll
        for (int rr = 0; rr < 2; ++rr) {
            #pragma unroll
            for (int j = 0; j < 6; ++j) {
                float4 vv = (j < 4) ? hreg[rr][j] : xreg[rr][j - 4];
                #pragma unroll
                for (int i = 0; i < 4; ++i) {
                    const float vi = F4C(vv, i);
                    #pragma unroll
                    for (int c = 0; c < 8; ++c)
                        pa[rr][c] = fmaf(vi, w1r[j][i][c], pa[rr][c]);
                }
            }
            if (t > 0) {
                #pragma unroll
                for (int j = 0; j < 4; ++j) {
                    float4 vv = hreg[rr][j];
                    #pragma unroll
                    for (int i = 0; i < 4; ++i) {
                        const float vi = F4C(vv, i);
                        #pragma unroll
                        for (int o = 0; o < 4; ++o)
                            py[rr][o] = fmaf(vi, w2r[j][i][o], py[rr][o]);
                    }
                }
            }
        }
        // ---- partials to swizzled scratch ----
        #pragma unroll
        for (int rr = 0; rr < 2; ++rr) {
            const int row = r2 + (rr << 3);
            #pragma unroll
            for (int c = 0; c < 8; ++c)
                sc_h[((row << 3) + c) * 32 + (g ^ (c << 2))] = pa[rr][c];
            if (t > 0)
                #pragma unroll
                for (int o = 0; o < 4; ++o)
                    sc_y[((row << 2) + o) * 32 + (g ^ (o << 2))] = py[rr][o];
        }
        __syncthreads();                           // SYNC1

        if (tid < 128) {
            // ---- h finish: reduce 32, tanh, publish ----
            float s = 0.f;
            #pragma unroll
            for (int j = 0; j < 8; ++j) {
                float4 q = *(const float4*)&sc_h[(tid << 5) + ((j << 2) ^ (oc << 2))];
                s += (q.x + q.y) + (q.z + q.w);
            }
            float hnew = tanhf(s + b1v);
            float* hdst = (float*)hb[(t + 1) & 1];
            __hip_atomic_store(&hdst[(size_t)(R0 + (tid >> 3)) * HH + C0 + oc], hnew,
                               __ATOMIC_RELAXED, __HIP_MEMORY_SCOPE_AGENT);
            if (t == TT - 1)
                out[OUT_OFF + (size_t)(R0 + (tid >> 3)) * HH + C0 + oc] = hnew;
            asm volatile("s_waitcnt vmcnt(0)" ::: "memory");   // per-wave drain
            if ((tid & 63) == 0)
                __hip_atomic_store(&mytag[tid >> 6], t + 1,
                                   __ATOMIC_RELAXED, __HIP_MEMORY_SCOPE_AGENT);
        } else if (tid < 192 && t > 0) {
            // ---- y finish: y_{t-1} ----
            float s = 0.f;
            #pragma unroll
            for (int j = 0; j < 8; ++j) {
                float4 q = *(const float4*)&sc_y[(yi << 5) + ((j << 2) ^ (yo << 2))];
                s += (q.x + q.y) + (q.z + q.w);
            }
            out[((size_t)(R0 + yrow) * TT + (t - 1)) * OO + O0 + yo] = s + b2v;
        }
    }

    // ---- epilogue: y_{TT-1} from h_TT ----
    if (tid < 128)
        while (__hip_atomic_load(ptag, __ATOMIC_RELAXED,
                                 __HIP_MEMORY_SCOPE_AGENT) < TT) {}
    __syncthreads();
    {
        float4 hreg[2][4];
        const ull* hsrc = hb[TT & 1];
        #pragma unroll
        for (int rr = 0; rr < 2; ++rr) {
            const ull* rp = hsrc + (size_t)(R0 + r2 + (rr << 3)) * (HH / 2) + (g << 1);
            #pragma unroll
            for (int j = 0; j < 4; ++j)
                hreg[rr][j] = ld_h4(rp + j * 64);
        }
        float py[2][4];
        #pragma unroll
        for (int rr = 0; rr < 2; ++rr) {
            #pragma unroll
            for (int o = 0; o < 4; ++o) py[rr][o] = 0.f;
            #pragma unroll
            for (int j = 0; j < 4; ++j) {
                float4 vv = hreg[rr][j];
                #pragma unroll
                for (int i = 0; i < 4; ++i) {
                    const float vi = F4C(vv, i);
                    #pragma unroll
                    for (int o = 0; o < 4; ++o)
                        py[rr][o] = fmaf(vi, w2r[j][i][o], py[rr][o]);
                }
            }
            const int row = r2 + (rr << 3);
            #pragma unroll
            for (int o = 0; o < 4; ++o)
                sc_y[((row << 2) + o) * 32 + (g ^ (o << 2))] = py[rr][o];
        }
        __syncthreads();
        if (tid >= 128 && tid < 192) {
            float s = 0.f;
            #pragma unroll
            for (int j = 0; j < 8; ++j) {
                float4 q = *(const float4*)&sc_y[(yi << 5) + ((j << 2) ^ (yo << 2))];
                s += (q.x + q.y) + (q.z + q.w);
            }
            out[((size_t)(R0 + yrow) * TT + (TT - 1)) * OO + O0 + yo] = s + b2v;
        }
    }
}

extern "C" void kernel_launch(void* const* d_in, const int* in_sizes, int n_in,
                              void* d_out, int out_size, void* d_ws, size_t ws_size,
                              hipStream_t stream) {
    const float* x  = (const float*)d_in[0];
    const float* W1 = (const float*)d_in[1];
    const float* b1 = (const float*)d_in[2];
    const float* W2 = (const float*)d_in[3];
    const float* b2 = (const float*)d_in[4];
    float* out = (float*)d_out;

    int*   tags = (int*)d_ws;
    float* hbuf = (float*)((char*)d_ws + 4096);   // tags padded to 4KB

    rnn_init<<<dim3(2), dim3(256), 0, stream>>>(tags);
    rnn_persist<<<dim3(NBLK), dim3(256), 0, stream>>>(x, W1, b1, W2, b2, out,
                                                      tags, hbuf);
}